// Round 5
// baseline (386.354 us; speedup 1.0000x reference)
//
#include <hip/hip_runtime.h>
#include <cstdint>

#define NITEMS   100000
#define BROWS    512
#define DDIM     64
#define NC       128                // items per chunk/block
#define NCHUNKS  782                // ceil(100000/128)

// ---------------- Threefry-2x32-20, key = (0, 42)  (jax.random.key(42)) ----
// VERIFIED (R4, absmax 0.0): partitionable scheme, counters (hi=0, lo=e),
// output = bits1 ^ bits2. Do not change.
__device__ __forceinline__ uint32_t threefry_0_42_xor(uint32_t e) {
    const uint32_t K1 = 42u;
    const uint32_t K2 = 0x1BD11BDAu ^ 42u;   // K0 = 0
    uint32_t x0 = 0u;           // counts_hi + K0 (=0)
    uint32_t x1 = e + K1;       // counts_lo + K1
#define TFR(r) { x0 += x1; x1 = (x1 << (r)) | (x1 >> (32 - (r))); x1 ^= x0; }
    TFR(13) TFR(15) TFR(26) TFR(6)
    x0 += K1;  x1 += K2 + 1u;
    TFR(17) TFR(29) TFR(16) TFR(24)
    x0 += K2;  x1 += 2u;               // + K0 + 2
    TFR(13) TFR(15) TFR(26) TFR(6)
    /* x0 += K0 (=0) */ x1 += K1 + 3u;
    TFR(17) TFR(29) TFR(16) TFR(24)
    x0 += K1;  x1 += K2 + 4u;
    TFR(13) TFR(15) TFR(26) TFR(6)
    x0 += K2;  x1 += 5u;               // + K0 + 5
#undef TFR
    return x0 ^ x1;                     // bits1 ^ bits2
}

// jax uniform(tiny,1) -> gumbel = -log(-log(u)); precise logf is REQUIRED:
// winners have u ~ 1 where fast v_log_f32's absolute error (~2^-21) becomes
// huge relative error in -log(u), flipping argmax.
__device__ __forceinline__ float gumbel_from_bits(uint32_t b) {
    float f = __uint_as_float((b >> 9) | 0x3F800000u) - 1.0f;   // [0,1)
    f = fmaxf(f, 1.17549435e-38f);                               // tiny clamp
    return -logf(-logf(f));
}

// orderable mapping for float -> uint32 (monotone)
__device__ __forceinline__ uint32_t order_map(float v) {
    uint32_t x = __float_as_uint(v);
    return (x & 0x80000000u) ? ~x : (x | 0x80000000u);
}

// ---------------- Kernel A: uif = UF @ W.T + b ; also init packed ----------
__global__ void uif_kernel(const float* __restrict__ UF,    // 512 x 128
                           const float* __restrict__ W,     // 64 x 128
                           const float* __restrict__ bias,  // 64
                           float* __restrict__ uif,         // 512 x 64
                           unsigned long long* __restrict__ packed) {
    int b = blockIdx.x;     // 512
    int d = threadIdx.x;    // 64
    if (d == 0) packed[b] = 0ull;
    const float* w = W + d * 128;
    const float* u = UF + b * 128;
    float s = 0.f;
    for (int k = 0; k < 128; k++) s = fmaf(u[k], w[k], s);
    uif[b * 64 + d] = s + bias[d];
}

// ---------------- Kernel B: score + gumbel, per-row argmax via atomicMax ---
// grid = (NCHUNKS, 2): blockIdx.x = item chunk, blockIdx.y = row group.
// 1 row per thread -> u[64] fits registers (R4's 2-row version showed
// VGPR_Count=84 < 128 floats => compiler wasn't keeping rows resident).
__global__ __launch_bounds__(256, 5) void score_argmax_kernel(
        const float* __restrict__ A,     // NITEMS x 64
        const float* __restrict__ uif,   // 512 x 64
        unsigned long long* __restrict__ packed) {
    __shared__ float As[NC * DDIM];      // 32 KB
    const int tid = threadIdx.x;
    const int row = blockIdx.y * 256 + tid;    // 0..511

    // own uif row in registers (64 VGPRs)
    float u[DDIM];
    {
        const float4* uif4 = (const float4*)(uif + row * DDIM);
#pragma unroll
        for (int k = 0; k < 16; k++) {
            float4 a = uif4[k];
            u[4*k] = a.x; u[4*k+1] = a.y; u[4*k+2] = a.z; u[4*k+3] = a.w;
        }
    }

    const int nbase  = blockIdx.x * NC;
    const int nvalid = min(NC, NITEMS - nbase);

    // stage A chunk to LDS (coalesced float4)
    {
        const float4* Ag  = (const float4*)(A + (size_t)nbase * DDIM);
        float4*       As4 = (float4*)As;
        const int cnt = nvalid * (DDIM / 4);
        for (int i = tid; i < cnt; i += 256) As4[i] = Ag[i];
    }
    __syncthreads();

    float best = -3.0e38f;
    int   bi   = 0;
    const uint32_t ebase = (uint32_t)row * (uint32_t)NITEMS + (uint32_t)nbase;

    for (int j = 0; j < nvalid; j++) {
        uint32_t r = threefry_0_42_xor(ebase + (uint32_t)j);
        float    g = gumbel_from_bits(r);

        // dot(u, A[j]) — wave-uniform LDS address => broadcast, 0 conflicts
        float s0 = 0.f, s1 = 0.f;
        const float4* a4 = (const float4*)(As + j * DDIM);
#pragma unroll
        for (int k = 0; k < 16; k += 2) {
            float4 x = a4[k];
            float4 y = a4[k + 1];
            s0 = fmaf(x.x, u[4*k    ], s0);
            s0 = fmaf(x.y, u[4*k + 1], s0);
            s0 = fmaf(x.z, u[4*k + 2], s0);
            s0 = fmaf(x.w, u[4*k + 3], s0);
            s1 = fmaf(y.x, u[4*k + 4], s1);
            s1 = fmaf(y.y, u[4*k + 5], s1);
            s1 = fmaf(y.z, u[4*k + 6], s1);
            s1 = fmaf(y.w, u[4*k + 7], s1);
        }
        float v = (s0 + s1) + g;
        if (v > best) { best = v; bi = nbase + j; }
    }

    // pack: high32 = orderable value, low32 = ~idx (ties -> lowest idx wins)
    unsigned long long pk =
        ((unsigned long long)order_map(best) << 32) | (uint32_t)(~(uint32_t)bi);
    atomicMax(&packed[row], pk);
}

// ---------------- Kernel C: decode idx, gather feat, cosine sim ------------
__global__ void finalize_kernel(const unsigned long long* __restrict__ packed,
                                const float* __restrict__ A,
                                const int* __restrict__ need_replace,
                                float* __restrict__ out,
                                float* __restrict__ sims) {
    int b    = blockIdx.x;   // 512
    int lane = threadIdx.x;  // 64
    unsigned long long pk = packed[b];
    int idx = (int)(~(uint32_t)(pk & 0xFFFFFFFFull));

    float fr = A[(size_t)idx * DDIM + lane];
    out[512 + b * DDIM + lane] = fr;                 // replaceable_feat

    int   item = need_replace[2 * b + 1];
    float fa   = A[(size_t)item * DDIM + lane];

    float dot = fa * fr, na2 = fa * fa, nb2 = fr * fr;
#pragma unroll
    for (int o = 32; o >= 1; o >>= 1) {
        dot += __shfl_down(dot, o);
        na2 += __shfl_down(na2, o);
        nb2 += __shfl_down(nb2, o);
    }
    if (lane == 0) {
        out[b] = (float)idx;                         // replaceable_items
        float denom = fmaxf(sqrtf(na2) * sqrtf(nb2), 1e-6f);
        float sim = dot / denom;
        sims[b] = (sim + 1.0f) * 0.5f;
    }
}

// ---------------- Kernel D: loss scalars -----------------------------------
__global__ void loss_kernel(const float* __restrict__ sims,
                            float* __restrict__ out) {
    __shared__ float shL[8], shS[8];
    int t = threadIdx.x;                 // 512 threads
    float s = sims[t];
    float d = s - 0.5f;
    float l = d * d;
#pragma unroll
    for (int o = 32; o >= 1; o >>= 1) {
        l += __shfl_down(l, o);
        s += __shfl_down(s, o);
    }
    int w = t >> 6;
    if ((t & 63) == 0) { shL[w] = l; shS[w] = s; }
    __syncthreads();
    if (t == 0) {
        float L = 0.f, S = 0.f;
        for (int i = 0; i < 8; i++) { L += shL[i]; S += shS[i]; }
        out[512 + 512 * DDIM]     = L / 512.0f;      // similarity_loss
        out[512 + 512 * DDIM + 1] = S / 512.0f;      // mean(sim)
    }
}

extern "C" void kernel_launch(void* const* d_in, const int* in_sizes, int n_in,
                              void* d_out, int out_size, void* d_ws, size_t ws_size,
                              hipStream_t stream) {
    (void)in_sizes; (void)n_in; (void)out_size; (void)ws_size;
    const int*   need_replace = (const int*)d_in[0];
    const float* UF           = (const float*)d_in[1];
    const float* A            = (const float*)d_in[2];
    const float* W            = (const float*)d_in[3];
    const float* bias         = (const float*)d_in[4];
    float* out = (float*)d_out;

    char* ws = (char*)d_ws;
    float*              uif    = (float*)ws;                         // 131072 B
    unsigned long long* packed = (unsigned long long*)(ws + 131072); // 4096 B
    float*              sims   = (float*)(ws + 131072 + 4096);       // 2048 B

    uif_kernel<<<BROWS, DDIM, 0, stream>>>(UF, W, bias, uif, packed);
    dim3 grid(NCHUNKS, 2);
    score_argmax_kernel<<<grid, 256, 0, stream>>>(A, uif, packed);
    finalize_kernel<<<BROWS, DDIM, 0, stream>>>(packed, A, need_replace, out, sims);
    loss_kernel<<<1, 512, 0, stream>>>(sims, out);
}

// Round 6
// 294.651 us; speedup vs baseline: 1.3112x; 1.3112x over previous
//
#include <hip/hip_runtime.h>
#include <cstdint>

#define NITEMS   100000
#define BROWS    512
#define DDIM     64
#define S_BLOCKS 391        // phase-1 item-blocks (256 items each)
#define IPB      256        // items per phase-1 block
#define NCHUNKS  782        // fallback chunks of 128 items
#define FB_Y     16

typedef __attribute__((ext_vector_type(8)))  short  bf16x8;   // 8 bf16 (4 VGPR)
typedef __attribute__((ext_vector_type(16))) float  f32x16;
typedef unsigned long long u64;
typedef uint32_t u32;

// ---------------- Threefry-2x32-20, key=(0,42). VERIFIED R4 (absmax 0.0):
// partitionable scheme, counters (hi=0, lo=e), output = bits1 ^ bits2.
__device__ __forceinline__ u32 threefry_0_42_xor(u32 e) {
    const u32 K1 = 42u;
    const u32 K2 = 0x1BD11BDAu ^ 42u;   // K0 = 0
    u32 x0 = 0u;
    u32 x1 = e + K1;
#define TFR(r) { x0 += x1; x1 = (x1 << (r)) | (x1 >> (32 - (r))); x1 ^= x0; }
    TFR(13) TFR(15) TFR(26) TFR(6)
    x0 += K1;  x1 += K2 + 1u;
    TFR(17) TFR(29) TFR(16) TFR(24)
    x0 += K2;  x1 += 2u;
    TFR(13) TFR(15) TFR(26) TFR(6)
    x1 += K1 + 3u;
    TFR(17) TFR(29) TFR(16) TFR(24)
    x0 += K1;  x1 += K2 + 4u;
    TFR(13) TFR(15) TFR(26) TFR(6)
    x0 += K2;  x1 += 5u;
#undef TFR
    return x0 ^ x1;
}

// jax uniform(tiny,1) -> gumbel = -log(-log(u)); precise logf REQUIRED.
__device__ __forceinline__ float gumbel_from_bits(u32 b) {
    float f = __uint_as_float((b >> 9) | 0x3F800000u) - 1.0f;
    f = fmaxf(f, 1.17549435e-38f);
    return -logf(-logf(f));
}

__device__ __forceinline__ u32 order_map(float v) {
    u32 x = __float_as_uint(v);
    return (x & 0x80000000u) ? ~x : (x | 0x80000000u);
}
__device__ __forceinline__ float unpack_val(u64 p) {
    u32 x = (u32)(p >> 32);
    u32 f = (x & 0x80000000u) ? (x & 0x7FFFFFFFu) : ~x;
    return __uint_as_float(f);
}

__device__ __forceinline__ short f32_to_bf16_rne(float f) {
    u32 b = __float_as_uint(f);
    u32 r = (b + 0x7FFFu + ((b >> 16) & 1u)) >> 16;
    return (short)r;
}
__device__ __forceinline__ float bf16_to_f32(short h) {
    return __uint_as_float(((u32)(uint16_t)h) << 16);
}

// ---------------- K1: uif = UF@W.T + b ; row norms; init scalars ----------
__global__ void uif_kernel(const float* __restrict__ UF, const float* __restrict__ W,
                           const float* __restrict__ bias, float* __restrict__ uif,
                           float* __restrict__ unorm, u32* __restrict__ amax_bits,
                           int* __restrict__ cnt) {
    int b = blockIdx.x, d = threadIdx.x;
    if (b == 0 && d == 0) { *cnt = 0; *amax_bits = 0u; }
    const float* w = W + d * 128;
    const float* u = UF + b * 128;
    float s = 0.f;
    for (int k = 0; k < 128; k++) s = fmaf(u[k], w[k], s);
    s += bias[d];
    uif[b * 64 + d] = s;
    float q = s * s;
#pragma unroll
    for (int o = 32; o >= 1; o >>= 1) q += __shfl_xor(q, o);
    if (d == 0) unorm[b] = sqrtf(q);
}

// ---------------- K2: max item norm ---------------------------------------
__global__ void anorm_kernel(const float* __restrict__ A, u32* __restrict__ amax_bits) {
    int item = blockIdx.x * 256 + threadIdx.x;
    float q = 0.f;
    if (item < NITEMS) {
        const float4* r = (const float4*)(A + (size_t)item * DDIM);
#pragma unroll
        for (int k = 0; k < 16; k++) {
            float4 x = r[k];
            q = fmaf(x.x, x.x, q); q = fmaf(x.y, x.y, q);
            q = fmaf(x.z, x.z, q); q = fmaf(x.w, x.w, q);
        }
    }
    float n = sqrtf(q);
#pragma unroll
    for (int o = 32; o >= 1; o >>= 1) n = fmaxf(n, __shfl_xor(n, o));
    if ((threadIdx.x & 63) == 0) atomicMax(amax_bits, __float_as_uint(n));
}

// ---------------- K3: phase-1 MFMA score + gumbel + per-row top-2 ---------
// grid (S_BLOCKS, 4). block 256 = 4 waves; wave wv owns rows rg*128+wv*32+(lane&31).
// C-tile (items x rows) via mfma_32x32x16_bf16, 3-term split uh*ah+ul*ah+uh*al.
__global__ __launch_bounds__(256, 3) void phase1_kernel(
        const float* __restrict__ A, const float* __restrict__ uif,
        u64* __restrict__ wsT1, float* __restrict__ wsT2) {
    __shared__ bf16x8 sh_ah[4 * 64];   // [step][frag-lane] 4KB
    __shared__ bf16x8 sh_al[4 * 64];
    const int tid  = threadIdx.x;
    const int lane = tid & 63;
    const int wv   = tid >> 6;
    const int rg   = blockIdx.y;
    const int sb   = blockIdx.x;
    const int itembase = sb * IPB;
    const int ntiles = min(8, (NITEMS - itembase + 31) >> 5);
    const int row   = rg * 128 + wv * 32 + (lane & 31);
    const int khalf = (lane >> 5) * 8;

    // B-operand frags for this wave's 32 uif rows: uh/ul (persistent)
    bf16x8 uh[4], ul[4];
#pragma unroll
    for (int s = 0; s < 4; s++) {
        const float* src = uif + row * 64 + khalf + 16 * s;
        float4 v0 = *(const float4*)src;
        float4 v1 = *(const float4*)(src + 4);
        float vv[8] = {v0.x, v0.y, v0.z, v0.w, v1.x, v1.y, v1.z, v1.w};
        bf16x8 h, l2;
#pragma unroll
        for (int j = 0; j < 8; j++) {
            short hh = f32_to_bf16_rne(vv[j]);
            float r  = vv[j] - bf16_to_f32(hh);
            h[j] = hh; l2[j] = f32_to_bf16_rne(r);
        }
        uh[s] = h; ul[s] = l2;
    }

    u64 t1p = 0ull; float t1f = -3.0e38f, t2f = -3.0e38f;
    const u32 rowbase_e = (u32)row * (u32)NITEMS;

    for (int t = 0; t < ntiles; t++) {
        const int tb = itembase + t * 32;
        __syncthreads();
        {   // stage + convert A tile into fragment layout
            const int i = tid >> 3, c = tid & 7;
            const float* src = A + (size_t)(tb + i) * 64 + 8 * c;
            float4 v0 = *(const float4*)src;
            float4 v1 = *(const float4*)(src + 4);
            float vv[8] = {v0.x, v0.y, v0.z, v0.w, v1.x, v1.y, v1.z, v1.w};
            bf16x8 h, l2;
#pragma unroll
            for (int j = 0; j < 8; j++) {
                short hh = f32_to_bf16_rne(vv[j]);
                float r  = vv[j] - bf16_to_f32(hh);
                h[j] = hh; l2[j] = f32_to_bf16_rne(r);
            }
            const int dst = (c >> 1) * 64 + (i & 31) + 32 * (c & 1);
            sh_ah[dst] = h; sh_al[dst] = l2;
        }
        __syncthreads();

        f32x16 acc;
#pragma unroll
        for (int z = 0; z < 16; z++) acc[z] = 0.0f;
#pragma unroll
        for (int s = 0; s < 4; s++) {
            bf16x8 ah = sh_ah[s * 64 + lane];
            bf16x8 al = sh_al[s * 64 + lane];
            acc = __builtin_amdgcn_mfma_f32_32x32x16_bf16(ah, uh[s], acc, 0, 0, 0);
            acc = __builtin_amdgcn_mfma_f32_32x32x16_bf16(al, uh[s], acc, 0, 0, 0);
            acc = __builtin_amdgcn_mfma_f32_32x32x16_bf16(ah, ul[s], acc, 0, 0, 0);
        }

        // epilogue: C[item_local = (i&3)+8*(i>>2)+4*(lane>>5)][rowcol = lane&31]
        const int ib4 = tb + 4 * (lane >> 5);
#pragma unroll
        for (int i = 0; i < 16; i++) {
            const int il   = (i & 3) + 8 * (i >> 2);
            const int item = ib4 + il;
            u32 rb  = threefry_0_42_xor(rowbase_e + (u32)item);
            float g = gumbel_from_bits(rb);
            float v = acc[i] + g;
            if (v > t1f) {
                t2f = t1f; t1f = v;
                t1p = ((u64)order_map(v) << 32) | (u32)(~(u32)item);
            } else {
                t2f = fmaxf(t2f, v);
            }
        }
    }

    // merge the two lanes sharing this row (lane ^ 32)
    {
        u64   op = __shfl_xor(t1p, 32);
        float of = __shfl_xor(t1f, 32);
        float o2 = __shfl_xor(t2f, 32);
        if (op > t1p) { t2f = fmaxf(t1f, o2); t1p = op; t1f = of; }
        else          { t2f = fmaxf(t2f, of); }
    }
    if (lane < 32) {
        wsT1[(size_t)row * S_BLOCKS + sb] = t1p;
        wsT2[(size_t)row * S_BLOCKS + sb] = t2f;
    }
}

// ---------------- K4: merge per-row top-2, certify gap, or flag -----------
__global__ void merge_kernel(const u64* __restrict__ wsT1, const float* __restrict__ wsT2,
                             const float* __restrict__ unorm, const u32* __restrict__ amax_bits,
                             u64* __restrict__ packed, int* __restrict__ rowlist,
                             int* __restrict__ cnt) {
    const int row = blockIdx.x, t = threadIdx.x;
    u64 p1 = 0ull; float f1 = -3.0e38f, f2 = -3.0e38f;
    for (int sbk = t; sbk < S_BLOCKS; sbk += 64) {
        u64 ep   = wsT1[(size_t)row * S_BLOCKS + sbk];
        float e2 = wsT2[(size_t)row * S_BLOCKS + sbk];
        if (ep > p1) { f2 = fmaxf(f1, e2); p1 = ep; f1 = unpack_val(ep); }
        else         { f2 = fmaxf(f2, unpack_val(ep)); }
    }
#pragma unroll
    for (int off = 1; off < 64; off <<= 1) {
        u64   op  = __shfl_xor(p1, off);
        float of1 = __shfl_xor(f1, off);
        float of2 = __shfl_xor(f2, off);
        if (op > p1) { f2 = fmaxf(f1, of2); p1 = op; f1 = of1; }
        else         { f2 = fmaxf(f2, of1); }
    }
    if (t == 0) {
        float Amax = __uint_as_float(*amax_bits);
        // |s~ - s_np| <= ~4.6e-5*|u||a| (split drop) + ~3e-5 (f32 accum, both
        // sides) + gumbel ulps; use 1.5e-4*|u|*Amax + 3e-5 (>=5x margin).
        float E = 1.5e-4f * unorm[row] * Amax + 3.0e-5f;
        if ((f1 - f2) > 2.0f * E) {
            packed[row] = p1;                       // certified exact argmax
        } else {
            packed[row] = 0ull;
            rowlist[atomicAdd(cnt, 1)] = row;       // rare: exact rescan
        }
    }
}

// ---------------- K5: exact f32 fallback for flagged rows -----------------
__global__ void fallback_kernel(const float* __restrict__ A, const float* __restrict__ uif,
                                const int* __restrict__ rowlist, const int* __restrict__ cnt,
                                u64* __restrict__ packed) {
    __shared__ float As[128 * 65];
    __shared__ float Us[64];
    const int t  = threadIdx.x;          // 0..127
    const int c  = blockIdx.x;           // chunk
    const int n0 = c * 128;
    const int nitem = min(128, NITEMS - n0);
    const int total = *cnt;
    if ((int)blockIdx.y >= total) return;

    if (t < nitem) {                     // stage A chunk once (row-padded +1)
        const float4* src = (const float4*)(A + (size_t)(n0 + t) * 64);
#pragma unroll
        for (int k4 = 0; k4 < 16; k4++) {
            float4 x = src[k4];
            As[t * 65 + 4 * k4 + 0] = x.x; As[t * 65 + 4 * k4 + 1] = x.y;
            As[t * 65 + 4 * k4 + 2] = x.z; As[t * 65 + 4 * k4 + 3] = x.w;
        }
    }
    for (int li = blockIdx.y; li < total; li += FB_Y) {
        const int row = rowlist[li];
        __syncthreads();
        if (t < 64) Us[t] = uif[row * 64 + t];
        __syncthreads();
        u64 pk = 0ull;
        if (t < nitem) {
            const int item = n0 + t;
            u32 rb  = threefry_0_42_xor((u32)row * (u32)NITEMS + (u32)item);
            float g = gumbel_from_bits(rb);
            float s0 = 0.f, s1 = 0.f;
#pragma unroll
            for (int k8 = 0; k8 < 64; k8 += 8) {   // same op order as R5 (verified)
                s0 = fmaf(As[t * 65 + k8 + 0], Us[k8 + 0], s0);
                s0 = fmaf(As[t * 65 + k8 + 1], Us[k8 + 1], s0);
                s0 = fmaf(As[t * 65 + k8 + 2], Us[k8 + 2], s0);
                s0 = fmaf(As[t * 65 + k8 + 3], Us[k8 + 3], s0);
                s1 = fmaf(As[t * 65 + k8 + 4], Us[k8 + 4], s1);
                s1 = fmaf(As[t * 65 + k8 + 5], Us[k8 + 5], s1);
                s1 = fmaf(As[t * 65 + k8 + 6], Us[k8 + 6], s1);
                s1 = fmaf(As[t * 65 + k8 + 7], Us[k8 + 7], s1);
            }
            float v = (s0 + s1) + g;
            pk = ((u64)order_map(v) << 32) | (u32)(~(u32)item);
        }
#pragma unroll
        for (int off = 1; off < 64; off <<= 1) {
            u64 o = __shfl_xor(pk, off);
            pk = (o > pk) ? o : pk;
        }
        if ((t & 63) == 0) atomicMax(&packed[row], pk);
        __syncthreads();
    }
}

// ---------------- K6: decode idx, gather feat, cosine sim -----------------
__global__ void finalize_kernel(const u64* __restrict__ packed, const float* __restrict__ A,
                                const int* __restrict__ need_replace,
                                float* __restrict__ out, float* __restrict__ sims) {
    int b = blockIdx.x, lane = threadIdx.x;
    u64 pk = packed[b];
    int idx = (int)(~(u32)(pk & 0xFFFFFFFFull));
    float fr = A[(size_t)idx * DDIM + lane];
    out[512 + b * DDIM + lane] = fr;
    int   item = need_replace[2 * b + 1];
    float fa   = A[(size_t)item * DDIM + lane];
    float dot = fa * fr, na2 = fa * fa, nb2 = fr * fr;
#pragma unroll
    for (int o = 32; o >= 1; o >>= 1) {
        dot += __shfl_down(dot, o);
        na2 += __shfl_down(na2, o);
        nb2 += __shfl_down(nb2, o);
    }
    if (lane == 0) {
        out[b] = (float)idx;
        float denom = fmaxf(sqrtf(na2) * sqrtf(nb2), 1e-6f);
        sims[b] = (dot / denom + 1.0f) * 0.5f;
    }
}

// ---------------- K7: loss scalars ----------------------------------------
__global__ void loss_kernel(const float* __restrict__ sims, float* __restrict__ out) {
    __shared__ float shL[8], shS[8];
    int t = threadIdx.x;
    float s = sims[t];
    float d = s - 0.5f;
    float l = d * d;
#pragma unroll
    for (int o = 32; o >= 1; o >>= 1) { l += __shfl_down(l, o); s += __shfl_down(s, o); }
    int w = t >> 6;
    if ((t & 63) == 0) { shL[w] = l; shS[w] = s; }
    __syncthreads();
    if (t == 0) {
        float L = 0.f, S = 0.f;
        for (int i = 0; i < 8; i++) { L += shL[i]; S += shS[i]; }
        out[512 + 512 * DDIM]     = L / 512.0f;
        out[512 + 512 * DDIM + 1] = S / 512.0f;
    }
}

extern "C" void kernel_launch(void* const* d_in, const int* in_sizes, int n_in,
                              void* d_out, int out_size, void* d_ws, size_t ws_size,
                              hipStream_t stream) {
    (void)in_sizes; (void)n_in; (void)out_size; (void)ws_size;
    const int*   need_replace = (const int*)d_in[0];
    const float* UF           = (const float*)d_in[1];
    const float* A            = (const float*)d_in[2];
    const float* W            = (const float*)d_in[3];
    const float* bias         = (const float*)d_in[4];
    float* out = (float*)d_out;

    char* ws = (char*)d_ws;                             // ~2.43 MB total
    u64*   wsT1    = (u64*)  (ws);                      // 512*391*8 = 1601536
    float* wsT2    = (float*)(ws + 1601536);            // 800768
    float* uif     = (float*)(ws + 2402304);            // 131072
    u64*   packed  = (u64*)  (ws + 2533376);            // 4096
    float* unorm   = (float*)(ws + 2537472);            // 2048
    float* sims    = (float*)(ws + 2539520);            // 2048
    int*   rowlist = (int*)  (ws + 2541568);            // 2048
    u32*   amax    = (u32*)  (ws + 2543616);            // 4
    int*   cnt     = (int*)  (ws + 2543620);            // 4

    uif_kernel<<<BROWS, 64, 0, stream>>>(UF, W, bias, uif, unorm, amax, cnt);
    anorm_kernel<<<S_BLOCKS, 256, 0, stream>>>(A, amax);
    phase1_kernel<<<dim3(S_BLOCKS, 4), 256, 0, stream>>>(A, uif, wsT1, wsT2);
    merge_kernel<<<BROWS, 64, 0, stream>>>(wsT1, wsT2, unorm, amax, packed, rowlist, cnt);
    fallback_kernel<<<dim3(NCHUNKS, FB_Y), 128, 0, stream>>>(A, uif, rowlist, cnt, packed);
    finalize_kernel<<<BROWS, 64, 0, stream>>>(packed, A, need_replace, out, sims);
    loss_kernel<<<1, 512, 0, stream>>>(sims, out);
}

// Round 7
// 259.321 us; speedup vs baseline: 1.4899x; 1.1362x over previous
//
#include <hip/hip_runtime.h>
#include <cstdint>

#define NITEMS   100000
#define BROWS    512
#define DDIM     64
#define S_BLOCKS 391        // phase-1 item-blocks (256 items each)
#define IPB      256
#define NCHUNKS  782        // fallback chunks of 128 items
#define FB_Y     8
#define OUT_FEAT 512
#define OUT_LOSS (512 + 512 * 64)
#define OUT_MSIM (OUT_LOSS + 1)

// Gumbel filter: g monotone in bits. bits>>9 >= BITS23_T <=> g may exceed 6.0.
// Skipped items have g < G_TE strictly (incl. logf rounding margin).
#define BITS23_T   8367841u
#define BITS_RAW_T 4284334592u      // BITS23_T << 9
#define G_TE       6.001f

typedef __attribute__((ext_vector_type(8)))  short  bf16x8;
typedef __attribute__((ext_vector_type(16))) float  f32x16;
typedef unsigned long long u64;
typedef uint32_t u32;

// ---------------- Threefry-2x32-20, key=(0,42). VERIFIED R4 (absmax 0.0):
// partitionable scheme, counters (hi=0, lo=e), output = bits1 ^ bits2.
__device__ __forceinline__ u32 threefry_0_42_xor(u32 e) {
    const u32 K1 = 42u;
    const u32 K2 = 0x1BD11BDAu ^ 42u;   // K0 = 0
    u32 x0 = 0u;
    u32 x1 = e + K1;
#define TFR(r) { x0 += x1; x1 = (x1 << (r)) | (x1 >> (32 - (r))); x1 ^= x0; }
    TFR(13) TFR(15) TFR(26) TFR(6)
    x0 += K1;  x1 += K2 + 1u;
    TFR(17) TFR(29) TFR(16) TFR(24)
    x0 += K2;  x1 += 2u;
    TFR(13) TFR(15) TFR(26) TFR(6)
    x1 += K1 + 3u;
    TFR(17) TFR(29) TFR(16) TFR(24)
    x0 += K1;  x1 += K2 + 4u;
    TFR(13) TFR(15) TFR(26) TFR(6)
    x0 += K2;  x1 += 5u;
#undef TFR
    return x0 ^ x1;
}

// jax uniform(tiny,1) -> gumbel = -log(-log(u)); precise logf REQUIRED.
__device__ __forceinline__ float gumbel_from_bits(u32 b) {
    float f = __uint_as_float((b >> 9) | 0x3F800000u) - 1.0f;
    f = fmaxf(f, 1.17549435e-38f);
    return -logf(-logf(f));
}

__device__ __forceinline__ u32 order_map(float v) {
    u32 x = __float_as_uint(v);
    return (x & 0x80000000u) ? ~x : (x | 0x80000000u);
}
__device__ __forceinline__ float unpack_val(u64 p) {
    u32 x = (u32)(p >> 32);
    u32 f = (x & 0x80000000u) ? (x & 0x7FFFFFFFu) : ~x;
    return __uint_as_float(f);
}
__device__ __forceinline__ short f32_to_bf16_rne(float f) {
    u32 b = __float_as_uint(f);
    u32 r = (b + 0x7FFFu + ((b >> 16) & 1u)) >> 16;
    return (short)r;
}
__device__ __forceinline__ float bf16_to_f32(short h) {
    return __uint_as_float(((u32)(uint16_t)h) << 16);
}

// ---------------- K1: prep = uif GEMM + row norms + item-norm partials -----
// blocks 0..127: 4 uif rows each (wave per row). blocks 128..518: item norms.
__global__ void prep_kernel(const float* __restrict__ UF, const float* __restrict__ W,
                            const float* __restrict__ bias, const float* __restrict__ A,
                            float* __restrict__ uif, float* __restrict__ unorm,
                            float* __restrict__ wsAM4, int* __restrict__ cnt) {
    const int t = threadIdx.x, b = blockIdx.x;
    if (b == 0 && t == 0) *cnt = 0;
    if (b < 128) {
        const int row = b * 4 + (t >> 6);
        const int d   = t & 63;
        const float* w = W + d * 128;
        const float* u = UF + row * 128;
        float s = 0.f;
        for (int k = 0; k < 128; k++) s = fmaf(u[k], w[k], s);
        s += bias[d];
        uif[row * 64 + d] = s;
        float q = s * s;
#pragma unroll
        for (int o = 32; o >= 1; o >>= 1) q += __shfl_xor(q, o);
        if (d == 0) unorm[row] = sqrtf(q);
    } else {
        const int item = (b - 128) * 256 + t;
        float q = 0.f;
        if (item < NITEMS) {
            const float4* r = (const float4*)(A + (size_t)item * DDIM);
#pragma unroll
            for (int k = 0; k < 16; k++) {
                float4 x = r[k];
                q = fmaf(x.x, x.x, q); q = fmaf(x.y, x.y, q);
                q = fmaf(x.z, x.z, q); q = fmaf(x.w, x.w, q);
            }
        }
        float n = sqrtf(q);
#pragma unroll
        for (int o = 32; o >= 1; o >>= 1) n = fmaxf(n, __shfl_xor(n, o));
        if ((t & 63) == 0) wsAM4[(b - 128) * 4 + (t >> 6)] = n;
    }
}

// ---------------- K2: phase-1 MFMA score + filtered gumbel + top-2 ---------
__global__ __launch_bounds__(256, 4) void phase1_kernel(
        const float* __restrict__ A, const float* __restrict__ uif,
        u64* __restrict__ wsT1, float* __restrict__ wsB) {
    __shared__ bf16x8 sh_ah[4 * 64];
    __shared__ bf16x8 sh_al[4 * 64];
    const int tid  = threadIdx.x;
    const int lane = tid & 63;
    const int wv   = tid >> 6;
    const int rg   = blockIdx.y;
    const int sb   = blockIdx.x;
    const int itembase = sb * IPB;
    const int ntiles = min(8, (NITEMS - itembase + 31) >> 5);
    const int row   = rg * 128 + wv * 32 + (lane & 31);
    const int khalf = (lane >> 5) * 8;

    bf16x8 uh[4], ul[4];
#pragma unroll
    for (int s = 0; s < 4; s++) {
        const float* src = uif + row * 64 + khalf + 16 * s;
        float4 v0 = *(const float4*)src;
        float4 v1 = *(const float4*)(src + 4);
        float vv[8] = {v0.x, v0.y, v0.z, v0.w, v1.x, v1.y, v1.z, v1.w};
        bf16x8 h, l2;
#pragma unroll
        for (int j = 0; j < 8; j++) {
            short hh = f32_to_bf16_rne(vv[j]);
            float r  = vv[j] - bf16_to_f32(hh);
            h[j] = hh; l2[j] = f32_to_bf16_rne(r);
        }
        uh[s] = h; ul[s] = l2;
    }

    u64 t1p = 0ull; float t1f = -3.0e38f, t2f = -3.0e38f, sm = -3.0e38f;
    const u32 rowbase_e = (u32)row * (u32)NITEMS;

    // staging: i = tid&31 (tile item), c = tid>>5 (8-float col chunk)
    // -> LDS write addr = lane-contiguous 16B (conflict-free, R6 had 8-way).
    const int s_i   = tid & 31;
    const int s_c   = tid >> 5;
    const int s_dst = (s_c >> 1) * 64 + s_i + 32 * (s_c & 1);   // same dst<->(i,c) as R6 (verified)
    const float* s_srcbase = A + (size_t)s_i * 64 + 8 * s_c;

    for (int t = 0; t < ntiles; t++) {
        const int tb = itembase + t * 32;
        __syncthreads();
        {
            const float* src = s_srcbase + (size_t)tb * 64;
            float4 v0 = *(const float4*)src;
            float4 v1 = *(const float4*)(src + 4);
            float vv[8] = {v0.x, v0.y, v0.z, v0.w, v1.x, v1.y, v1.z, v1.w};
            bf16x8 h, l2;
#pragma unroll
            for (int j = 0; j < 8; j++) {
                short hh = f32_to_bf16_rne(vv[j]);
                float r  = vv[j] - bf16_to_f32(hh);
                h[j] = hh; l2[j] = f32_to_bf16_rne(r);
            }
            sh_ah[s_dst] = h; sh_al[s_dst] = l2;
        }
        __syncthreads();

        f32x16 acc;
#pragma unroll
        for (int z = 0; z < 16; z++) acc[z] = 0.0f;
#pragma unroll
        for (int s = 0; s < 4; s++) {
            bf16x8 ah = sh_ah[s * 64 + lane];
            bf16x8 al = sh_al[s * 64 + lane];
            acc = __builtin_amdgcn_mfma_f32_32x32x16_bf16(ah, uh[s], acc, 0, 0, 0);
            acc = __builtin_amdgcn_mfma_f32_32x32x16_bf16(al, uh[s], acc, 0, 0, 0);
            acc = __builtin_amdgcn_mfma_f32_32x32x16_bf16(ah, ul[s], acc, 0, 0, 0);
        }

        const int ib4 = tb + 4 * (lane >> 5);
#pragma unroll
        for (int i = 0; i < 16; i++) {
            const int il   = (i & 3) + 8 * (i >> 2);
            const int item = ib4 + il;
            u32 rb  = threefry_0_42_xor(rowbase_e + (u32)item);
            float s = acc[i];
            sm = fmaxf(sm, s);
            if (rb >= BITS_RAW_T) {               // ~0.25% of items
                float g = gumbel_from_bits(rb);
                float v = s + g;
                if (v > t1f) {
                    t2f = t1f; t1f = v;
                    t1p = ((u64)order_map(v) << 32) | (u32)(~(u32)item);
                } else t2f = fmaxf(t2f, v);
            }
        }
    }

    // bound channel: second-best candidate OR skipped-item bound
    float bnd = fmaxf(t2f, sm + G_TE);
    {
        u64   op = __shfl_xor(t1p, 32);
        float of = __shfl_xor(t1f, 32);
        float ob = __shfl_xor(bnd, 32);
        if (op > t1p) { bnd = fmaxf(fmaxf(bnd, ob), t1f); t1p = op; t1f = of; }
        else          { bnd = fmaxf(fmaxf(bnd, ob), of); }
    }
    if (lane < 32) {
        wsT1[(size_t)row * S_BLOCKS + sb] = t1p;
        wsB [(size_t)row * S_BLOCKS + sb] = bnd;
    }
}

// ---------------- K3: merge top1/bound, certify gap, flag + zero loss ------
__global__ void merge_kernel(const u64* __restrict__ wsT1, const float* __restrict__ wsB,
                             const float* __restrict__ wsAM4, const float* __restrict__ unorm,
                             u64* __restrict__ packed, int* __restrict__ rowlist,
                             int* __restrict__ cnt, float* __restrict__ out) {
    const int row = blockIdx.x, t = threadIdx.x;
    if (row == 0 && t == 0) { out[OUT_LOSS] = 0.f; out[OUT_MSIM] = 0.f; }
    float am = 0.f;
    for (int i = t; i < S_BLOCKS * 4; i += 64) am = fmaxf(am, wsAM4[i]);
    u64 p1 = 0ull; float f1 = -3.0e38f, f2 = -3.0e38f;
    for (int sbk = t; sbk < S_BLOCKS; sbk += 64) {
        u64   ep = wsT1[(size_t)row * S_BLOCKS + sbk];
        float e2 = wsB [(size_t)row * S_BLOCKS + sbk];
        if (ep > p1) { f2 = fmaxf(fmaxf(f1, e2), f2); p1 = ep; f1 = unpack_val(ep); }
        else         { float v = unpack_val(ep); f2 = fmaxf(f2, fmaxf(v, e2)); }
    }
#pragma unroll
    for (int off = 1; off < 64; off <<= 1) {
        u64   op  = __shfl_xor(p1, off);
        float of1 = __shfl_xor(f1, off);
        float of2 = __shfl_xor(f2, off);
        am = fmaxf(am, __shfl_xor(am, off));
        if (op > p1) { f2 = fmaxf(fmaxf(f1, of2), f2); p1 = op; f1 = of1; }
        else         { f2 = fmaxf(f2, fmaxf(of1, of2)); }
    }
    if (t == 0) {
        float E = 1.5e-4f * unorm[row] * am + 3.0e-5f;   // R6-verified margin
        if (f1 - f2 > 2.0f * E) {
            packed[row] = p1;
        } else {
            packed[row] = 0ull;
            rowlist[atomicAdd(cnt, 1)] = row;
        }
    }
}

// ---------------- K4: exact f32 fallback for flagged rows ------------------
__global__ void fallback_kernel(const float* __restrict__ A, const float* __restrict__ uif,
                                const int* __restrict__ rowlist, const int* __restrict__ cnt,
                                u64* __restrict__ packed) {
    __shared__ float As[128 * 65];
    __shared__ float Us[64];
    const int t  = threadIdx.x;          // 0..127
    const int c  = blockIdx.x;
    const int n0 = c * 128;
    const int nitem = min(128, NITEMS - n0);
    const int total = *cnt;
    if ((int)blockIdx.y >= total) return;

    if (t < nitem) {
        const float4* src = (const float4*)(A + (size_t)(n0 + t) * 64);
#pragma unroll
        for (int k4 = 0; k4 < 16; k4++) {
            float4 x = src[k4];
            As[t * 65 + 4 * k4 + 0] = x.x; As[t * 65 + 4 * k4 + 1] = x.y;
            As[t * 65 + 4 * k4 + 2] = x.z; As[t * 65 + 4 * k4 + 3] = x.w;
        }
    }
    for (int li = blockIdx.y; li < total; li += FB_Y) {
        const int row = rowlist[li];
        __syncthreads();
        if (t < 64) Us[t] = uif[row * 64 + t];
        __syncthreads();
        u64 pk = 0ull;
        if (t < nitem) {
            const int item = n0 + t;
            u32 rb  = threefry_0_42_xor((u32)row * (u32)NITEMS + (u32)item);
            float g = gumbel_from_bits(rb);
            float s0 = 0.f, s1 = 0.f;
#pragma unroll
            for (int k8 = 0; k8 < 64; k8 += 8) {   // R5-verified op order
                s0 = fmaf(As[t * 65 + k8 + 0], Us[k8 + 0], s0);
                s0 = fmaf(As[t * 65 + k8 + 1], Us[k8 + 1], s0);
                s0 = fmaf(As[t * 65 + k8 + 2], Us[k8 + 2], s0);
                s0 = fmaf(As[t * 65 + k8 + 3], Us[k8 + 3], s0);
                s1 = fmaf(As[t * 65 + k8 + 4], Us[k8 + 4], s1);
                s1 = fmaf(As[t * 65 + k8 + 5], Us[k8 + 5], s1);
                s1 = fmaf(As[t * 65 + k8 + 6], Us[k8 + 6], s1);
                s1 = fmaf(As[t * 65 + k8 + 7], Us[k8 + 7], s1);
            }
            float v = (s0 + s1) + g;
            pk = ((u64)order_map(v) << 32) | (u32)(~(u32)item);
        }
#pragma unroll
        for (int off = 1; off < 64; off <<= 1) {
            u64 o = __shfl_xor(pk, off);
            pk = (o > pk) ? o : pk;
        }
        if ((t & 63) == 0) atomicMax(&packed[row], pk);
        __syncthreads();
    }
}

// ---------------- K5: resolve = finalize + loss (scaled atomics) -----------
__global__ void resolve_kernel(const u64* __restrict__ packed, const float* __restrict__ A,
                               const int* __restrict__ need_replace, float* __restrict__ out) {
    int b = blockIdx.x, lane = threadIdx.x;
    u64 pk = packed[b];
    int idx = (int)(~(u32)(pk & 0xFFFFFFFFull));
    float fr = A[(size_t)idx * DDIM + lane];
    out[OUT_FEAT + b * DDIM + lane] = fr;
    int   item = need_replace[2 * b + 1];
    float fa   = A[(size_t)item * DDIM + lane];
    float dot = fa * fr, na2 = fa * fa, nb2 = fr * fr;
#pragma unroll
    for (int o = 32; o >= 1; o >>= 1) {
        dot += __shfl_down(dot, o);
        na2 += __shfl_down(na2, o);
        nb2 += __shfl_down(nb2, o);
    }
    if (lane == 0) {
        out[b] = (float)idx;
        float denom = fmaxf(sqrtf(na2) * sqrtf(nb2), 1e-6f);
        float sim = (dot / denom + 1.0f) * 0.5f;
        float d = sim - 0.5f;
        atomicAdd(&out[OUT_LOSS], d * d * (1.0f / 512.0f));
        atomicAdd(&out[OUT_MSIM], sim * (1.0f / 512.0f));
    }
}

extern "C" void kernel_launch(void* const* d_in, const int* in_sizes, int n_in,
                              void* d_out, int out_size, void* d_ws, size_t ws_size,
                              hipStream_t stream) {
    (void)in_sizes; (void)n_in; (void)out_size; (void)ws_size;
    const int*   need_replace = (const int*)d_in[0];
    const float* UF           = (const float*)d_in[1];
    const float* A            = (const float*)d_in[2];
    const float* W            = (const float*)d_in[3];
    const float* bias         = (const float*)d_in[4];
    float* out = (float*)d_out;

    char* ws = (char*)d_ws;                              // ~2.55 MB total
    u64*   wsT1    = (u64*)  (ws);                       // 512*391*8 = 1601536
    float* wsB     = (float*)(ws + 1601536);             // 800768
    float* uif     = (float*)(ws + 2402304);             // 131072
    u64*   packed  = (u64*)  (ws + 2533376);             // 4096
    float* unorm   = (float*)(ws + 2537472);             // 2048
    float* wsAM4   = (float*)(ws + 2539520);             // 6256
    int*   rowlist = (int*)  (ws + 2545776);             // 2048
    int*   cnt     = (int*)  (ws + 2547824);             // 4

    prep_kernel<<<519, 256, 0, stream>>>(UF, W, bias, A, uif, unorm, wsAM4, cnt);
    phase1_kernel<<<dim3(S_BLOCKS, 4), 256, 0, stream>>>(A, uif, wsT1, wsB);
    merge_kernel<<<BROWS, 64, 0, stream>>>(wsT1, wsB, wsAM4, unorm, packed, rowlist, cnt, out);
    fallback_kernel<<<dim3(NCHUNKS, FB_Y), 128, 0, stream>>>(A, uif, rowlist, cnt, packed);
    resolve_kernel<<<BROWS, 64, 0, stream>>>(packed, A, need_replace, out);
}